// Round 5
// baseline (902.344 us; speedup 1.0000x reference)
//
#include <hip/hip_runtime.h>
#include <math.h>

#define N_ROWS 4096
#define E_DIM  512
#define C_CLS  50257
#define NCT    786          // ceil(50257/64) col-tiles -> partials per row
#define COS_M  (-0.6536436208636119f)   // cos(4.0)
#define SIN_M  (-0.7568024953079282f)   // sin(4.0)
#define EPSN   1e-12f

typedef __bf16 bf16x8 __attribute__((ext_vector_type(8)));
typedef float  f32x4  __attribute__((ext_vector_type(4)));
typedef unsigned short ushort8 __attribute__((ext_vector_type(8)));

__device__ inline unsigned short f2bf(float f) {
  unsigned int u = __float_as_uint(f);
  u += 0x7FFFu + ((u >> 16) & 1u);     // round-to-nearest-even
  return (unsigned short)(u >> 16);
}

// w row L2-normalize, wave-private (no barriers): 4 rows/block, 1 wave/row.
__global__ __launch_bounds__(256) void k_norm_w(const float* __restrict__ src,
                                                unsigned short* __restrict__ dst) {
  int row = blockIdx.x * 4 + (threadIdx.x >> 6);
  if (row >= C_CLS) return;
  int lane = threadIdx.x & 63;
  const float4* p = (const float4*)(src + (size_t)row * E_DIM);
  float4 v0 = p[lane * 2], v1 = p[lane * 2 + 1];
  float ss = v0.x*v0.x + v0.y*v0.y + v0.z*v0.z + v0.w*v0.w
           + v1.x*v1.x + v1.y*v1.y + v1.z*v1.z + v1.w*v1.w;
  #pragma unroll
  for (int m = 32; m > 0; m >>= 1) ss += __shfl_xor(ss, m, 64);
  float inv = 1.0f / fmaxf(sqrtf(ss), EPSN);
  ushort8 o;
  o[0]=f2bf(v0.x*inv); o[1]=f2bf(v0.y*inv); o[2]=f2bf(v0.z*inv); o[3]=f2bf(v0.w*inv);
  o[4]=f2bf(v1.x*inv); o[5]=f2bf(v1.y*inv); o[6]=f2bf(v1.z*inv); o[7]=f2bf(v1.w*inv);
  *(ushort8*)(dst + (size_t)row * E_DIM + lane * 8) = o;
}

// x row L2-normalize + precise fp32 target cosine (fused). 1 block/row, 256 thr.
__global__ __launch_bounds__(256) void k_norm_x(const float* __restrict__ x,
                                                const float* __restrict__ w,
                                                const int* __restrict__ label,
                                                unsigned short* __restrict__ nx,
                                                float* __restrict__ tv) {
  int row = blockIdx.x;
  int lab = label[row];
  int tid = threadIdx.x;
  const float2* px = (const float2*)(x + (size_t)row * E_DIM);
  const float2* pw = (const float2*)(w + (size_t)lab * E_DIM);
  float2 a = px[tid], b = pw[tid];
  float sx = a.x*a.x + a.y*a.y;
  float sw = b.x*b.x + b.y*b.y;
  float sd = a.x*b.x + a.y*b.y;
  #pragma unroll
  for (int off = 32; off > 0; off >>= 1) {
    sx += __shfl_down(sx, off, 64);
    sw += __shfl_down(sw, off, 64);
    sd += __shfl_down(sd, off, 64);
  }
  __shared__ float sb[3][4];
  if ((tid & 63) == 0) {
    sb[0][tid >> 6] = sx; sb[1][tid >> 6] = sw; sb[2][tid >> 6] = sd;
  }
  __syncthreads();
  float SX = sb[0][0] + sb[0][1] + sb[0][2] + sb[0][3];
  float inv = 1.0f / fmaxf(sqrtf(SX), EPSN);
  ushort2 o;
  o.x = f2bf(a.x * inv);
  o.y = f2bf(a.y * inv);
  ((ushort2*)(nx + (size_t)row * E_DIM))[tid] = o;
  if (tid == 0) {
    float SW = sb[1][0] + sb[1][1] + sb[1][2] + sb[1][3];
    float SD = sb[2][0] + sb[2][1] + sb[2][2] + sb[2][3];
    tv[row] = SD / (fmaxf(sqrtf(SX), EPSN) * fmaxf(sqrtf(SW), EPSN));
  }
}

// Barrier-free wave-private GEMM + fused exp-sum. NO LDS.
// 1 wave (64 thr) per block; tile = 128 rows x 64 cols; BK=32, 16 K-iters.
// All fragments load direct global->register, double-buffered 1 iter ahead.
// With a single wave per block there is no sharing, so LDS staging would buy
// nothing: the global access pattern (16 rows x 64 B segments per fragment
// load) is identical. Compiler owns all vmcnt waits -> correct by construction.
// No max-prescan: cos in [-1,1] so exp() is safe; partials are plain sums.
__global__ __launch_bounds__(64, 2) void k_gemm(const unsigned short* __restrict__ nx,
                                                const unsigned short* __restrict__ nw,
                                                const int* __restrict__ label,
                                                float* __restrict__ pl,
                                                float* __restrict__ tbf) {
  int rtile = blockIdx.x;              // 0..31, fastest-varying -> B reuse in cache
  int ctile = blockIdx.y;              // 0..785
  int lane = threadIdx.x & 63;
  int q = lane >> 4;
  int l15 = lane & 15;
  int rowTile = rtile * 128;
  int colTile = ctile * 64;

  // A fragment (16x32) for subtile i: lane(q,l15) reads row rowTile+i*16+l15,
  // elems kt*32 + q*8 .. +7 (16 B).
  const unsigned short* gA = nx + (size_t)(rowTile + l15) * E_DIM + q * 8;
  // B: 4 col-subtiles of 16 classes.
  const unsigned short* gB[4];
  #pragma unroll
  for (int j = 0; j < 4; j++) {
    int cls = colTile + j * 16 + l15;
    if (cls >= C_CLS) cls = C_CLS - 1;          // clamp; masked in epilogue
    gB[j] = nw + (size_t)cls * E_DIM + q * 8;
  }

  bf16x8 afr[2][8], bfr[2][4];
  #pragma unroll
  for (int i = 0; i < 8; i++)
    afr[0][i] = *(const bf16x8*)(gA + (size_t)i * 16 * E_DIM);
  #pragma unroll
  for (int j = 0; j < 4; j++)
    bfr[0][j] = *(const bf16x8*)(gB[j]);

  f32x4 acc[8][4] = {};

  #pragma unroll
  for (int kt = 0; kt < 16; kt++) {
    int p = kt & 1;
    if (kt + 1 < 16) {
      #pragma unroll
      for (int i = 0; i < 8; i++)
        afr[p ^ 1][i] = *(const bf16x8*)(gA + (size_t)i * 16 * E_DIM + (kt + 1) * 32);
      #pragma unroll
      for (int j = 0; j < 4; j++)
        bfr[p ^ 1][j] = *(const bf16x8*)(gB[j] + (kt + 1) * 32);
    }
    #pragma unroll
    for (int i = 0; i < 8; i++)
      #pragma unroll
      for (int j = 0; j < 4; j++)
        acc[i][j] = __builtin_amdgcn_mfma_f32_16x16x32_bf16(afr[p][i], bfr[p][j],
                                                            acc[i][j], 0, 0, 0);
  }

  // Epilogue: C/D layout row = 4*q + reg (within 16), col = l15.
  #pragma unroll
  for (int i = 0; i < 8; i++) {
    #pragma unroll
    for (int reg = 0; reg < 4; reg++) {
      int grow = rowTile + i * 16 + 4 * q + reg;
      int lab = label[grow];
      float e = 0.f;
      #pragma unroll
      for (int j = 0; j < 4; j++) {
        int col = colTile + j * 16 + l15;
        float v = acc[i][j][reg];
        if (col < C_CLS) {
          e += __expf(v);
          if (col == lab) tbf[grow] = v;   // bf16-GEMM cos at label position
        }
      }
      #pragma unroll
      for (int m = 1; m < 16; m <<= 1) e += __shfl_xor(e, m, 64);
      if (l15 == 0) pl[(size_t)grow * NCT + ctile] = e;
    }
  }
}

// Sum per-tile exp-sums -> row denominator, swap in margin logit, mean-reduce.
__global__ __launch_bounds__(256) void k_reduce(const float* __restrict__ pl,
                                                const float* __restrict__ tv,
                                                const float* __restrict__ tbf,
                                                float* __restrict__ out) {
  int row = blockIdx.x;
  int tid = threadIdx.x;
  float s = 0.f;
  for (int j = tid; j < NCT; j += 256) s += pl[(size_t)row * NCT + j];
  __shared__ float sb[256];
  sb[tid] = s;
  __syncthreads();
  for (int k = 128; k > 0; k >>= 1) {
    if (tid < k) sb[tid] += sb[tid + k];
    __syncthreads();
  }
  if (tid == 0) {
    float S = sb[0];
    float t = tv[row];
    float tb = tbf[row];
    float sint = sqrtf(fmaxf(0.f, 1.f - t * t));
    float cosm = t * COS_M - sint * SIN_M;
    float Sp = S - __expf(tb) + __expf(cosm);   // replace target logit
    float loss = logf(Sp) - cosm;
    atomicAdd(out, loss * (1.0f / N_ROWS));
  }
}

extern "C" void kernel_launch(void* const* d_in, const int* in_sizes, int n_in,
                              void* d_out, int out_size, void* d_ws, size_t ws_size,
                              hipStream_t stream) {
  const float* x = (const float*)d_in[0];
  const int* label = (const int*)d_in[1];
  const float* w = (const float*)d_in[2];
  float* out = (float*)d_out;
  char* ws = (char*)d_ws;

  size_t off = 0;
  unsigned short* nx = (unsigned short*)(ws + off); off += (size_t)N_ROWS * E_DIM * 2;  // 4 MB
  unsigned short* nw = (unsigned short*)(ws + off); off += (size_t)C_CLS * E_DIM * 2;   // 51.5 MB
  float* tv  = (float*)(ws + off); off += (size_t)N_ROWS * 4;
  float* tbf = (float*)(ws + off); off += (size_t)N_ROWS * 4;
  float* pl  = (float*)(ws + off); off += (size_t)N_ROWS * NCT * 4;                     // 12.9 MB

  hipMemsetAsync(d_out, 0, sizeof(float), stream);
  k_norm_w<<<(C_CLS + 3) / 4, 256, 0, stream>>>(w, nw);
  k_norm_x<<<N_ROWS, 256, 0, stream>>>(x, w, label, nx, tv);
  dim3 g(N_ROWS / 128, NCT);
  k_gemm<<<g, 64, 0, stream>>>(nx, nw, label, pl, tbf);
  k_reduce<<<N_ROWS, 256, 0, stream>>>(pl, tv, tbf, out);
}

// Round 6
// 678.688 us; speedup vs baseline: 1.3295x; 1.3295x over previous
//
#include <hip/hip_runtime.h>
#include <math.h>

#define N_ROWS 4096
#define E_DIM  512
#define C_CLS  50257
#define NCT2   786          // partials per row: 393 col-tiles * 2 wave-halves
#define NTILE  393          // ceil(50257/128)
#define COS_M  (-0.6536436208636119f)   // cos(4.0)
#define SIN_M  (-0.7568024953079282f)   // sin(4.0)
#define EPSN   1e-12f

typedef __bf16 bf16x8 __attribute__((ext_vector_type(8)));
typedef float  f32x4  __attribute__((ext_vector_type(4)));
typedef unsigned short ushort8 __attribute__((ext_vector_type(8)));

__device__ inline unsigned short f2bf(float f) {
  unsigned int u = __float_as_uint(f);
  u += 0x7FFFu + ((u >> 16) & 1u);     // round-to-nearest-even
  return (unsigned short)(u >> 16);
}

// w row L2-normalize, wave-private (no barriers): 4 rows/block, 1 wave/row.
__global__ __launch_bounds__(256) void k_norm_w(const float* __restrict__ src,
                                                unsigned short* __restrict__ dst) {
  int row = blockIdx.x * 4 + (threadIdx.x >> 6);
  if (row >= C_CLS) return;
  int lane = threadIdx.x & 63;
  const float4* p = (const float4*)(src + (size_t)row * E_DIM);
  float4 v0 = p[lane * 2], v1 = p[lane * 2 + 1];
  float ss = v0.x*v0.x + v0.y*v0.y + v0.z*v0.z + v0.w*v0.w
           + v1.x*v1.x + v1.y*v1.y + v1.z*v1.z + v1.w*v1.w;
  #pragma unroll
  for (int m = 32; m > 0; m >>= 1) ss += __shfl_xor(ss, m, 64);
  float inv = 1.0f / fmaxf(sqrtf(ss), EPSN);
  ushort8 o;
  o[0]=f2bf(v0.x*inv); o[1]=f2bf(v0.y*inv); o[2]=f2bf(v0.z*inv); o[3]=f2bf(v0.w*inv);
  o[4]=f2bf(v1.x*inv); o[5]=f2bf(v1.y*inv); o[6]=f2bf(v1.z*inv); o[7]=f2bf(v1.w*inv);
  *(ushort8*)(dst + (size_t)row * E_DIM + lane * 8) = o;
}

// x row L2-normalize + precise fp32 target cosine (fused). 1 block/row, 256 thr.
__global__ __launch_bounds__(256) void k_norm_x(const float* __restrict__ x,
                                                const float* __restrict__ w,
                                                const int* __restrict__ label,
                                                unsigned short* __restrict__ nx,
                                                float* __restrict__ tv) {
  int row = blockIdx.x;
  int lab = label[row];
  int tid = threadIdx.x;
  const float2* px = (const float2*)(x + (size_t)row * E_DIM);
  const float2* pw = (const float2*)(w + (size_t)lab * E_DIM);
  float2 a = px[tid], b = pw[tid];
  float sx = a.x*a.x + a.y*a.y;
  float sw = b.x*b.x + b.y*b.y;
  float sd = a.x*b.x + a.y*b.y;
  #pragma unroll
  for (int off = 32; off > 0; off >>= 1) {
    sx += __shfl_down(sx, off, 64);
    sw += __shfl_down(sw, off, 64);
    sd += __shfl_down(sd, off, 64);
  }
  __shared__ float sb[3][4];
  if ((tid & 63) == 0) {
    sb[0][tid >> 6] = sx; sb[1][tid >> 6] = sw; sb[2][tid >> 6] = sd;
  }
  __syncthreads();
  float SX = sb[0][0] + sb[0][1] + sb[0][2] + sb[0][3];
  float inv = 1.0f / fmaxf(sqrtf(SX), EPSN);
  ushort2 o;
  o.x = f2bf(a.x * inv);
  o.y = f2bf(a.y * inv);
  ((ushort2*)(nx + (size_t)row * E_DIM))[tid] = o;
  if (tid == 0) {
    float SW = sb[1][0] + sb[1][1] + sb[1][2] + sb[1][3];
    float SD = sb[2][0] + sb[2][1] + sb[2][2] + sb[2][3];
    tv[row] = SD / (fmaxf(sqrtf(SX), EPSN) * fmaxf(sqrtf(SW), EPSN));
  }
}

// 128x128-tile GEMM (cos = nx.nw^T) + fused exp-sum.
// 4 waves (2x2 quadrants of 64x64). BK=32, 16 stages, DOUBLE-buffered LDS,
// ONE barrier per stage; stage k+1 global_load_lds issued BEFORE the stage-k
// ds_read+MFMA, so the vmcnt drain at the barrier is covered by compute.
// Cross-wave hazard check: writes into buf p^1 at iter k are safe because all
// waves' ds_reads of buf p^1 (stage k-1) completed before barrier k-1.
// LDS layout = MFMA fragment order (chunk = 64 lanes x 16 B contiguous).
// No max-prescan: cos in [-1,1] so exp() is safe; partials are plain sums.
// Grid (rtile fastest): linear id = ctile*32+rtile -> XCD ~ rtile%8, so each
// XCD's L2 holds a 512 KB A-slice (4 rtiles) + streaming B tiles.
__global__ __launch_bounds__(256) void k_gemm(const unsigned short* __restrict__ nx,
                                              const unsigned short* __restrict__ nw,
                                              const int* __restrict__ label,
                                              float* __restrict__ pl,
                                              float* __restrict__ tbf) {
  __shared__ bf16x8 ldsA[2][8 * 64];   // 2 x 8 KB
  __shared__ bf16x8 ldsB[2][8 * 64];   // 2 x 8 KB

  int rtile = blockIdx.x;              // 0..31 fastest
  int ctile = blockIdx.y;              // 0..392
  int tid = threadIdx.x;
  int wave = tid >> 6;
  int lane = tid & 63;
  int q = lane >> 4;
  int l15 = lane & 15;
  int wr = wave >> 1;
  int wc = wave & 1;
  int rowTile = rtile * 128;
  int colTile = ctile * 128;

  // Each wave stages A-chunks {2w,2w+1} and B-chunks {2w,2w+1} per stage.
  // Chunk c covers rows/cols [c*16, +16); lane (q,l15) supplies
  // row c*16+l15, elems kt*32 + q*8 .. +7 (16 B).
  const unsigned short* gA[2];
  const unsigned short* gB[2];
  #pragma unroll
  for (int t = 0; t < 2; t++) {
    int c = wave * 2 + t;
    gA[t] = nx + (size_t)(rowTile + c * 16 + l15) * E_DIM + q * 8;
    int cls = colTile + c * 16 + l15;
    if (cls >= C_CLS) cls = C_CLS - 1;          // clamp; masked in epilogue
    gB[t] = nw + (size_t)cls * E_DIM + q * 8;
  }

  // Prologue: stage 0 into buffer 0.
  #pragma unroll
  for (int t = 0; t < 2; t++) {
    int c = wave * 2 + t;
    __builtin_amdgcn_global_load_lds(
        (const __attribute__((address_space(1))) void*)(gA[t]),
        (__attribute__((address_space(3))) void*)(&ldsA[0][c * 64]), 16, 0, 0);
    __builtin_amdgcn_global_load_lds(
        (const __attribute__((address_space(1))) void*)(gB[t]),
        (__attribute__((address_space(3))) void*)(&ldsB[0][c * 64]), 16, 0, 0);
  }

  f32x4 acc[4][4] = {};
  __syncthreads();   // stage 0 visible

  #pragma unroll
  for (int kt = 0; kt < 16; kt++) {
    int p = kt & 1;
    if (kt + 1 < 16) {
      #pragma unroll
      for (int t = 0; t < 2; t++) {
        int c = wave * 2 + t;
        __builtin_amdgcn_global_load_lds(
            (const __attribute__((address_space(1))) void*)(gA[t] + (kt + 1) * 32),
            (__attribute__((address_space(3))) void*)(&ldsA[p ^ 1][c * 64]), 16, 0, 0);
        __builtin_amdgcn_global_load_lds(
            (const __attribute__((address_space(1))) void*)(gB[t] + (kt + 1) * 32),
            (__attribute__((address_space(3))) void*)(&ldsB[p ^ 1][c * 64]), 16, 0, 0);
      }
    }
    bf16x8 afr[4], bfr[4];
    #pragma unroll
    for (int i = 0; i < 4; i++)
      afr[i] = ldsA[p][(wr * 4 + i) * 64 + lane];
    #pragma unroll
    for (int j = 0; j < 4; j++)
      bfr[j] = ldsB[p][(wc * 4 + j) * 64 + lane];
    #pragma unroll
    for (int i = 0; i < 4; i++)
      #pragma unroll
      for (int j = 0; j < 4; j++)
        acc[i][j] = __builtin_amdgcn_mfma_f32_16x16x32_bf16(afr[i], bfr[j],
                                                            acc[i][j], 0, 0, 0);
    __syncthreads();   // stage kt+1 visible; prefetch latency was covered
  }

  // Epilogue: C/D layout row = 4*q + reg (within 16), col = l15.
  // Wave covers rows [rowTile + wr*64, +64), cols [colTile + wc*64, +64).
  int colW = colTile + wc * 64;
  #pragma unroll
  for (int msub = 0; msub < 4; msub++) {
    #pragma unroll
    for (int reg = 0; reg < 4; reg++) {
      int grow = rowTile + wr * 64 + msub * 16 + 4 * q + reg;
      int lab = label[grow];
      float e = 0.f;
      #pragma unroll
      for (int ns = 0; ns < 4; ns++) {
        int col = colW + ns * 16 + l15;
        float v = acc[msub][ns][reg];
        if (col < C_CLS) {
          e += __expf(v);
          if (col == lab) tbf[grow] = v;   // bf16-GEMM cos at label position
        }
      }
      #pragma unroll
      for (int m = 1; m < 16; m <<= 1) e += __shfl_xor(e, m, 64);
      if (l15 == 0) pl[(size_t)grow * NCT2 + (size_t)ctile * 2 + wc] = e;
    }
  }
}

// Sum per-tile exp-sums -> row denominator, swap in margin logit, mean-reduce.
__global__ __launch_bounds__(256) void k_reduce(const float* __restrict__ pl,
                                               const float* __restrict__ tv,
                                               const float* __restrict__ tbf,
                                               float* __restrict__ out) {
  int row = blockIdx.x;
  int tid = threadIdx.x;
  float s = 0.f;
  for (int j = tid; j < NCT2; j += 256) s += pl[(size_t)row * NCT2 + j];
  __shared__ float sb[256];
  sb[tid] = s;
  __syncthreads();
  for (int k = 128; k > 0; k >>= 1) {
    if (tid < k) sb[tid] += sb[tid + k];
    __syncthreads();
  }
  if (tid == 0) {
    float S = sb[0];
    float t = tv[row];
    float tb = tbf[row];
    float sint = sqrtf(fmaxf(0.f, 1.f - t * t));
    float cosm = t * COS_M - sint * SIN_M;
    float Sp = S - __expf(tb) + __expf(cosm);   // replace target logit
    float loss = logf(Sp) - cosm;
    atomicAdd(out, loss * (1.0f / N_ROWS));
  }
}

extern "C" void kernel_launch(void* const* d_in, const int* in_sizes, int n_in,
                              void* d_out, int out_size, void* d_ws, size_t ws_size,
                              hipStream_t stream) {
  const float* x = (const float*)d_in[0];
  const int* label = (const int*)d_in[1];
  const float* w = (const float*)d_in[2];
  float* out = (float*)d_out;
  char* ws = (char*)d_ws;

  size_t off = 0;
  unsigned short* nx = (unsigned short*)(ws + off); off += (size_t)N_ROWS * E_DIM * 2;  // 4 MB
  unsigned short* nw = (unsigned short*)(ws + off); off += (size_t)C_CLS * E_DIM * 2;   // 51.5 MB
  float* tv  = (float*)(ws + off); off += (size_t)N_ROWS * 4;
  float* tbf = (float*)(ws + off); off += (size_t)N_ROWS * 4;
  float* pl  = (float*)(ws + off); off += (size_t)N_ROWS * NCT2 * 4;                    // 12.9 MB

  hipMemsetAsync(d_out, 0, sizeof(float), stream);
  k_norm_w<<<(C_CLS + 3) / 4, 256, 0, stream>>>(w, nw);
  k_norm_x<<<N_ROWS, 256, 0, stream>>>(x, w, label, nx, tv);
  dim3 g(N_ROWS / 128, NTILE);
  k_gemm<<<g, 256, 0, stream>>>(nx, nw, label, pl, tbf);
  k_reduce<<<N_ROWS, 256, 0, stream>>>(pl, tv, tbf, out);
}

// Round 7
// 668.270 us; speedup vs baseline: 1.3503x; 1.0156x over previous
//
#include <hip/hip_runtime.h>
#include <math.h>

#define N_ROWS 4096
#define E_DIM  512
#define C_CLS  50257
#define NCT2   786          // partials per row: 393 col-tiles * 2 wave-halves
#define NTILE  393          // ceil(50257/128)
#define COS_M  (-0.6536436208636119f)   // cos(4.0)
#define SIN_M  (-0.7568024953079282f)   // sin(4.0)
#define EPSN   1e-12f

// s_waitcnt immediates (gfx9 encoding: vmcnt[3:0]|exp[6:4]|lgkm[11:8]|vmcnt[5:4]<<14)
#define WAITCNT_VM4   0x0F74   // vmcnt(4),  lgkm/exp ignored
#define WAITCNT_VM0   0x0F70   // vmcnt(0),  lgkm/exp ignored
#define WAITCNT_LGKM0 0xC07F   // lgkmcnt(0), vmcnt/exp ignored

typedef __bf16 bf16x8 __attribute__((ext_vector_type(8)));
typedef float  f32x4  __attribute__((ext_vector_type(4)));
typedef unsigned short ushort8 __attribute__((ext_vector_type(8)));

__device__ inline unsigned short f2bf(float f) {
  unsigned int u = __float_as_uint(f);
  u += 0x7FFFu + ((u >> 16) & 1u);     // round-to-nearest-even
  return (unsigned short)(u >> 16);
}

// w row L2-normalize, wave-private (no barriers): 4 rows/block, 1 wave/row.
__global__ __launch_bounds__(256) void k_norm_w(const float* __restrict__ src,
                                                unsigned short* __restrict__ dst) {
  int row = blockIdx.x * 4 + (threadIdx.x >> 6);
  if (row >= C_CLS) return;
  int lane = threadIdx.x & 63;
  const float4* p = (const float4*)(src + (size_t)row * E_DIM);
  float4 v0 = p[lane * 2], v1 = p[lane * 2 + 1];
  float ss = v0.x*v0.x + v0.y*v0.y + v0.z*v0.z + v0.w*v0.w
           + v1.x*v1.x + v1.y*v1.y + v1.z*v1.z + v1.w*v1.w;
  #pragma unroll
  for (int m = 32; m > 0; m >>= 1) ss += __shfl_xor(ss, m, 64);
  float inv = 1.0f / fmaxf(sqrtf(ss), EPSN);
  ushort8 o;
  o[0]=f2bf(v0.x*inv); o[1]=f2bf(v0.y*inv); o[2]=f2bf(v0.z*inv); o[3]=f2bf(v0.w*inv);
  o[4]=f2bf(v1.x*inv); o[5]=f2bf(v1.y*inv); o[6]=f2bf(v1.z*inv); o[7]=f2bf(v1.w*inv);
  *(ushort8*)(dst + (size_t)row * E_DIM + lane * 8) = o;
}

// x row L2-normalize + precise fp32 target cosine (fused). 1 block/row, 256 thr.
__global__ __launch_bounds__(256) void k_norm_x(const float* __restrict__ x,
                                                const float* __restrict__ w,
                                                const int* __restrict__ label,
                                                unsigned short* __restrict__ nx,
                                                float* __restrict__ tv) {
  int row = blockIdx.x;
  int lab = label[row];
  int tid = threadIdx.x;
  const float2* px = (const float2*)(x + (size_t)row * E_DIM);
  const float2* pw = (const float2*)(w + (size_t)lab * E_DIM);
  float2 a = px[tid], b = pw[tid];
  float sx = a.x*a.x + a.y*a.y;
  float sw = b.x*b.x + b.y*b.y;
  float sd = a.x*b.x + a.y*b.y;
  #pragma unroll
  for (int off = 32; off > 0; off >>= 1) {
    sx += __shfl_down(sx, off, 64);
    sw += __shfl_down(sw, off, 64);
    sd += __shfl_down(sd, off, 64);
  }
  __shared__ float sb[3][4];
  if ((tid & 63) == 0) {
    sb[0][tid >> 6] = sx; sb[1][tid >> 6] = sw; sb[2][tid >> 6] = sd;
  }
  __syncthreads();
  float SX = sb[0][0] + sb[0][1] + sb[0][2] + sb[0][3];
  float inv = 1.0f / fmaxf(sqrtf(SX), EPSN);
  ushort2 o;
  o.x = f2bf(a.x * inv);
  o.y = f2bf(a.y * inv);
  ((ushort2*)(nx + (size_t)row * E_DIM))[tid] = o;
  if (tid == 0) {
    float SW = sb[1][0] + sb[1][1] + sb[1][2] + sb[1][3];
    float SD = sb[2][0] + sb[2][1] + sb[2][2] + sb[2][3];
    tv[row] = SD / (fmaxf(sqrtf(SX), EPSN) * fmaxf(sqrtf(SW), EPSN));
  }
}

// 128x128-tile GEMM (cos = nx.nw^T) + fused exp-sum.
// 4 waves (2x2 quadrants of 64x64). BK=32, 16 stages. TRIPLE-buffered LDS,
// depth-2 prefetch, raw s_barrier + MANUAL s_waitcnt vmcnt(4) — loads for
// stage k+1 stay in flight across the barrier (never a full drain in steady
// state). Stage k:
//   vmcnt(4)            -- own stage-k loads retired (k+1's 4 still in flight)
//   s_barrier           -- all waves' stage-k chunks now in LDS & visible
//   issue 4 loads k+2   -- into buf (k+2)%3 == (k-1)%3; safe: every wave's
//                          stage-(k-1) ds_reads retired before its stage-k
//                          barrier (lgkmcnt(0) precedes its MFMA)
//   ds_read buf k%3; lgkmcnt(0); 16 MFMA
// vmcnt retires in order, so any extra compiler-scheduled loads only
// over-wait (never under-wait). Full unroll keeps buffer indices constant.
// No max-prescan: cos in [-1,1] so exp() is safe; partials are plain sums.
__global__ __launch_bounds__(256, 3) void k_gemm(const unsigned short* __restrict__ nx,
                                                 const unsigned short* __restrict__ nw,
                                                 const int* __restrict__ label,
                                                 float* __restrict__ pl,
                                                 float* __restrict__ tbf) {
  __shared__ bf16x8 ldsA[3][8 * 64];   // 3 x 8 KB
  __shared__ bf16x8 ldsB[3][8 * 64];   // 3 x 8 KB

  int rtile = blockIdx.x;              // 0..31 fastest -> B reuse in L2/L3
  int ctile = blockIdx.y;              // 0..392
  int tid = threadIdx.x;
  int wave = tid >> 6;
  int lane = tid & 63;
  int q = lane >> 4;
  int l15 = lane & 15;
  int wr = wave >> 1;
  int wc = wave & 1;
  int rowTile = rtile * 128;
  int colTile = ctile * 128;

  // Each wave stages A-chunks {2w,2w+1} and B-chunks {2w,2w+1} per stage.
  // Chunk c covers rows/cols [c*16,+16); lane (q,l15) supplies row c*16+l15,
  // elems kt*32 + q*8 .. +7 (16 B). One inst = 64 lanes x 16 B = 1 KB chunk.
  const unsigned short* gA[2];
  const unsigned short* gB[2];
  #pragma unroll
  for (int t = 0; t < 2; t++) {
    int c = wave * 2 + t;
    gA[t] = nx + (size_t)(rowTile + c * 16 + l15) * E_DIM + q * 8;
    int cls = colTile + c * 16 + l15;
    if (cls >= C_CLS) cls = C_CLS - 1;          // clamp; masked in epilogue
    gB[t] = nw + (size_t)cls * E_DIM + q * 8;
  }

  // Prologue: stage 0 -> buf0, stage 1 -> buf1 (8 loads, issue order matters).
  #pragma unroll
  for (int s = 0; s < 2; s++) {
    #pragma unroll
    for (int t = 0; t < 2; t++) {
      int c = wave * 2 + t;
      __builtin_amdgcn_global_load_lds(
          (const __attribute__((address_space(1))) void*)(gA[t] + s * 32),
          (__attribute__((address_space(3))) void*)(&ldsA[s][c * 64]), 16, 0, 0);
      __builtin_amdgcn_global_load_lds(
          (const __attribute__((address_space(1))) void*)(gB[t] + s * 32),
          (__attribute__((address_space(3))) void*)(&ldsB[s][c * 64]), 16, 0, 0);
    }
  }

  f32x4 acc[4][4] = {};

  #pragma unroll
  for (int kt = 0; kt < 16; kt++) {
    if (kt < 15) __builtin_amdgcn_s_waitcnt(WAITCNT_VM4);
    else         __builtin_amdgcn_s_waitcnt(WAITCNT_VM0);
    __builtin_amdgcn_s_barrier();
    if (kt + 2 < 16) {
      int b2 = (kt + 2) % 3;
      #pragma unroll
      for (int t = 0; t < 2; t++) {
        int c = wave * 2 + t;
        __builtin_amdgcn_global_load_lds(
            (const __attribute__((address_space(1))) void*)(gA[t] + (kt + 2) * 32),
            (__attribute__((address_space(3))) void*)(&ldsA[b2][c * 64]), 16, 0, 0);
        __builtin_amdgcn_global_load_lds(
            (const __attribute__((address_space(1))) void*)(gB[t] + (kt + 2) * 32),
            (__attribute__((address_space(3))) void*)(&ldsB[b2][c * 64]), 16, 0, 0);
      }
    }
    int b = kt % 3;
    bf16x8 afr[4], bfr[4];
    #pragma unroll
    for (int i = 0; i < 4; i++)
      afr[i] = ldsA[b][(wr * 4 + i) * 64 + lane];
    #pragma unroll
    for (int j = 0; j < 4; j++)
      bfr[j] = ldsB[b][(wc * 4 + j) * 64 + lane];
    __builtin_amdgcn_s_waitcnt(WAITCNT_LGKM0);   // frags in regs before MFMA & next barrier
    #pragma unroll
    for (int i = 0; i < 4; i++)
      #pragma unroll
      for (int j = 0; j < 4; j++)
        acc[i][j] = __builtin_amdgcn_mfma_f32_16x16x32_bf16(afr[i], bfr[j],
                                                            acc[i][j], 0, 0, 0);
  }

  // Epilogue: C/D layout row = 4*q + reg (within 16), col = l15.
  // Wave covers rows [rowTile + wr*64, +64), cols [colTile + wc*64, +64).
  int colW = colTile + wc * 64;
  #pragma unroll
  for (int msub = 0; msub < 4; msub++) {
    #pragma unroll
    for (int reg = 0; reg < 4; reg++) {
      int grow = rowTile + wr * 64 + msub * 16 + 4 * q + reg;
      int lab = label[grow];
      float e = 0.f;
      #pragma unroll
      for (int ns = 0; ns < 4; ns++) {
        int col = colW + ns * 16 + l15;
        float v = acc[msub][ns][reg];
        if (col < C_CLS) {
          e += __expf(v);
          if (col == lab) tbf[grow] = v;   // bf16-GEMM cos at label position
        }
      }
      #pragma unroll
      for (int m = 1; m < 16; m <<= 1) e += __shfl_xor(e, m, 64);
      if (l15 == 0) pl[(size_t)grow * NCT2 + (size_t)ctile * 2 + wc] = e;
    }
  }
}

// Sum per-tile exp-sums -> row denominator, swap in margin logit, mean-reduce.
__global__ __launch_bounds__(256) void k_reduce(const float* __restrict__ pl,
                                               const float* __restrict__ tv,
                                               const float* __restrict__ tbf,
                                               float* __restrict__ out) {
  int row = blockIdx.x;
  int tid = threadIdx.x;
  float s = 0.f;
  for (int j = tid; j < NCT2; j += 256) s += pl[(size_t)row * NCT2 + j];
  __shared__ float sb[256];
  sb[tid] = s;
  __syncthreads();
  for (int k = 128; k > 0; k >>= 1) {
    if (tid < k) sb[tid] += sb[tid + k];
    __syncthreads();
  }
  if (tid == 0) {
    float S = sb[0];
    float t = tv[row];
    float tb = tbf[row];
    float sint = sqrtf(fmaxf(0.f, 1.f - t * t));
    float cosm = t * COS_M - sint * SIN_M;
    float Sp = S - __expf(tb) + __expf(cosm);   // replace target logit
    float loss = logf(Sp) - cosm;
    atomicAdd(out, loss * (1.0f / N_ROWS));
  }
}

extern "C" void kernel_launch(void* const* d_in, const int* in_sizes, int n_in,
                              void* d_out, int out_size, void* d_ws, size_t ws_size,
                              hipStream_t stream) {
  const float* x = (const float*)d_in[0];
  const int* label = (const int*)d_in[1];
  const float* w = (const float*)d_in[2];
  float* out = (float*)d_out;
  char* ws = (char*)d_ws;

  size_t off = 0;
  unsigned short* nx = (unsigned short*)(ws + off); off += (size_t)N_ROWS * E_DIM * 2;  // 4 MB
  unsigned short* nw = (unsigned short*)(ws + off); off += (size_t)C_CLS * E_DIM * 2;   // 51.5 MB
  float* tv  = (float*)(ws + off); off += (size_t)N_ROWS * 4;
  float* tbf = (float*)(ws + off); off += (size_t)N_ROWS * 4;
  float* pl  = (float*)(ws + off); off += (size_t)N_ROWS * NCT2 * 4;                    // 12.9 MB

  hipMemsetAsync(d_out, 0, sizeof(float), stream);
  k_norm_w<<<(C_CLS + 3) / 4, 256, 0, stream>>>(w, nw);
  k_norm_x<<<N_ROWS, 256, 0, stream>>>(x, w, label, nx, tv);
  dim3 g(N_ROWS / 128, NTILE);
  k_gemm<<<g, 256, 0, stream>>>(nx, nw, label, pl, tbf);
  k_reduce<<<N_ROWS, 256, 0, stream>>>(pl, tv, tbf, out);
}

// Round 8
// 602.896 us; speedup vs baseline: 1.4967x; 1.1084x over previous
//
#include <hip/hip_runtime.h>
#include <math.h>

#define N_ROWS 4096
#define E_DIM  512
#define C_CLS  50257
#define NCT2   786          // partials per row: 393 col-tiles * 2 wave-halves
#define NTILE  393          // ceil(50257/128)
#define COS_M  (-0.6536436208636119f)   // cos(4.0)
#define SIN_M  (-0.7568024953079282f)   // sin(4.0)
#define EPSN   1e-12f

#define WAITCNT_LGKM0 0xC07F   // lgkmcnt(0), vmcnt/exp ignored

typedef __bf16 bf16x8 __attribute__((ext_vector_type(8)));
typedef float  f32x4  __attribute__((ext_vector_type(4)));
typedef unsigned short ushort8 __attribute__((ext_vector_type(8)));

__device__ inline unsigned short f2bf(float f) {
  unsigned int u = __float_as_uint(f);
  u += 0x7FFFu + ((u >> 16) & 1u);     // round-to-nearest-even
  return (unsigned short)(u >> 16);
}

// w row L2-normalize, wave-private (no barriers): 4 rows/block, 1 wave/row.
__global__ __launch_bounds__(256) void k_norm_w(const float* __restrict__ src,
                                                unsigned short* __restrict__ dst) {
  int row = blockIdx.x * 4 + (threadIdx.x >> 6);
  if (row >= C_CLS) return;
  int lane = threadIdx.x & 63;
  const float4* p = (const float4*)(src + (size_t)row * E_DIM);
  float4 v0 = p[lane * 2], v1 = p[lane * 2 + 1];
  float ss = v0.x*v0.x + v0.y*v0.y + v0.z*v0.z + v0.w*v0.w
           + v1.x*v1.x + v1.y*v1.y + v1.z*v1.z + v1.w*v1.w;
  #pragma unroll
  for (int m = 32; m > 0; m >>= 1) ss += __shfl_xor(ss, m, 64);
  float inv = 1.0f / fmaxf(sqrtf(ss), EPSN);
  ushort8 o;
  o[0]=f2bf(v0.x*inv); o[1]=f2bf(v0.y*inv); o[2]=f2bf(v0.z*inv); o[3]=f2bf(v0.w*inv);
  o[4]=f2bf(v1.x*inv); o[5]=f2bf(v1.y*inv); o[6]=f2bf(v1.z*inv); o[7]=f2bf(v1.w*inv);
  *(ushort8*)(dst + (size_t)row * E_DIM + lane * 8) = o;
}

// x row L2-normalize + precise fp32 target cosine (fused). 1 block/row, 256 thr.
__global__ __launch_bounds__(256) void k_norm_x(const float* __restrict__ x,
                                                const float* __restrict__ w,
                                                const int* __restrict__ label,
                                                unsigned short* __restrict__ nx,
                                                float* __restrict__ tv) {
  int row = blockIdx.x;
  int lab = label[row];
  int tid = threadIdx.x;
  const float2* px = (const float2*)(x + (size_t)row * E_DIM);
  const float2* pw = (const float2*)(w + (size_t)lab * E_DIM);
  float2 a = px[tid], b = pw[tid];
  float sx = a.x*a.x + a.y*a.y;
  float sw = b.x*b.x + b.y*b.y;
  float sd = a.x*b.x + a.y*b.y;
  #pragma unroll
  for (int off = 32; off > 0; off >>= 1) {
    sx += __shfl_down(sx, off, 64);
    sw += __shfl_down(sw, off, 64);
    sd += __shfl_down(sd, off, 64);
  }
  __shared__ float sb[3][4];
  if ((tid & 63) == 0) {
    sb[0][tid >> 6] = sx; sb[1][tid >> 6] = sw; sb[2][tid >> 6] = sd;
  }
  __syncthreads();
  float SX = sb[0][0] + sb[0][1] + sb[0][2] + sb[0][3];
  float inv = 1.0f / fmaxf(sqrtf(SX), EPSN);
  ushort2 o;
  o.x = f2bf(a.x * inv);
  o.y = f2bf(a.y * inv);
  ((ushort2*)(nx + (size_t)row * E_DIM))[tid] = o;
  if (tid == 0) {
    float SW = sb[1][0] + sb[1][1] + sb[1][2] + sb[1][3];
    float SD = sb[2][0] + sb[2][1] + sb[2][2] + sb[2][3];
    tv[row] = SD / (fmaxf(sqrtf(SX), EPSN) * fmaxf(sqrtf(SW), EPSN));
  }
}

// 128x128-tile GEMM (cos = nx.nw^T) + fused exp-sum.
// CLASSIC register-staged pipeline — NO global_load_lds anywhere, so the
// compiler never ties vmcnt to LDS and the barrier drains lgkm ONLY;
// in-flight global loads (stage k+2) cross the barrier.
// 4 waves (2x2 quadrants of 64x64). BK=32, 16 stages, double-buffered LDS.
// Stage k (buf p=k&1 holds stage k; reg set (k+1)&1 holds stage k+1 data):
//   ds_read frags from buf p
//   ds_write reg set (k+1)&1 -> buf p^1   (precise per-reg vmcnt wait; loads
//                                          were issued 2 stages ago)
//   issue global loads stage k+2 -> reg set (k+2)&1 == p  (no wait)
//   16 MFMA (fine-grained lgkm waits on its ds_reads)
//   s_waitcnt lgkmcnt(0); s_barrier     (all LDS ops retired; vmcnt untouched)
// Hazards: buf p^1 writes at stage k are safe — every wave's stage-(k-1)
// reads of p^1 retired at its lgkmcnt(0) before barrier k-1. Reg parity sets
// alternate: set written to LDS at stage k is reloaded at stage k (for k+2).
// LDS layout = MFMA fragment order (chunk = 64 lanes x 16 B contiguous);
// b128 ops are 2-way bank aliased = free (m136).
// No max-prescan: cos in [-1,1] so exp() is safe; partials are plain sums.
__global__ __launch_bounds__(256, 4) void k_gemm(const unsigned short* __restrict__ nx,
                                                 const unsigned short* __restrict__ nw,
                                                 const int* __restrict__ label,
                                                 float* __restrict__ pl,
                                                 float* __restrict__ tbf) {
  __shared__ bf16x8 ldsA[2][8 * 64];   // 2 x 8 KB
  __shared__ bf16x8 ldsB[2][8 * 64];   // 2 x 8 KB

  int rtile = blockIdx.x;              // 0..31 fastest -> B reuse in L2/L3
  int ctile = blockIdx.y;              // 0..392
  int tid = threadIdx.x;
  int wave = tid >> 6;
  int lane = tid & 63;
  int q = lane >> 4;
  int l15 = lane & 15;
  int wr = wave >> 1;
  int wc = wave & 1;
  int rowTile = rtile * 128;
  int colTile = ctile * 128;

  // Chunk c = wave*2+t covers rows/cols [c*16,+16); lane (q,l15) supplies
  // row c*16+l15, elems kt*32 + q*8 .. +7 (16 B).
  const unsigned short* gA[2];
  const unsigned short* gB[2];
  #pragma unroll
  for (int t = 0; t < 2; t++) {
    int c = wave * 2 + t;
    gA[t] = nx + (size_t)(rowTile + c * 16 + l15) * E_DIM + q * 8;
    int cls = colTile + c * 16 + l15;
    if (cls >= C_CLS) cls = C_CLS - 1;          // clamp; masked in epilogue
    gB[t] = nw + (size_t)cls * E_DIM + q * 8;
  }

  // Staging registers: parity sets — set s&1 holds stage s data.
  bf16x8 rA[2][2], rB[2][2];
  #pragma unroll
  for (int t = 0; t < 2; t++) {
    rA[0][t] = *(const bf16x8*)(gA[t]);
    rB[0][t] = *(const bf16x8*)(gB[t]);
    rA[1][t] = *(const bf16x8*)(gA[t] + 32);
    rB[1][t] = *(const bf16x8*)(gB[t] + 32);
  }
  // Write stage 0 into buf 0 (compiler inserts precise vmcnt waits).
  #pragma unroll
  for (int t = 0; t < 2; t++) {
    int c = wave * 2 + t;
    ldsA[0][c * 64 + lane] = rA[0][t];
    ldsB[0][c * 64 + lane] = rB[0][t];
  }
  __builtin_amdgcn_s_waitcnt(WAITCNT_LGKM0);
  __builtin_amdgcn_s_barrier();

  f32x4 acc[4][4] = {};

  #pragma unroll
  for (int kt = 0; kt < 16; kt++) {
    int p = kt & 1;
    // Fragments for stage kt.
    bf16x8 afr[4], bfr[4];
    #pragma unroll
    for (int i = 0; i < 4; i++)
      afr[i] = ldsA[p][(wr * 4 + i) * 64 + lane];
    #pragma unroll
    for (int j = 0; j < 4; j++)
      bfr[j] = ldsB[p][(wc * 4 + j) * 64 + lane];
    // Stage kt+1: regs -> buf p^1.
    if (kt + 1 < 16) {
      #pragma unroll
      for (int t = 0; t < 2; t++) {
        int c = wave * 2 + t;
        ldsA[p ^ 1][c * 64 + lane] = rA[(kt + 1) & 1][t];
        ldsB[p ^ 1][c * 64 + lane] = rB[(kt + 1) & 1][t];
      }
    }
    // Stage kt+2: global -> regs (set (kt+2)&1 == p; consumed by the write above
    // at this stage, so WAR is resolved by the compiler's precise scheduling).
    if (kt + 2 < 16) {
      #pragma unroll
      for (int t = 0; t < 2; t++) {
        rA[p][t] = *(const bf16x8*)(gA[t] + (kt + 2) * 32);
        rB[p][t] = *(const bf16x8*)(gB[t] + (kt + 2) * 32);
      }
    }
    #pragma unroll
    for (int i = 0; i < 4; i++)
      #pragma unroll
      for (int j = 0; j < 4; j++)
        acc[i][j] = __builtin_amdgcn_mfma_f32_16x16x32_bf16(afr[i], bfr[j],
                                                            acc[i][j], 0, 0, 0);
    __builtin_amdgcn_s_waitcnt(WAITCNT_LGKM0);   // all LDS ops retired (vmcnt free)
    __builtin_amdgcn_s_barrier();
  }

  // Epilogue: C/D layout row = 4*q + reg (within 16), col = l15.
  // Wave covers rows [rowTile + wr*64, +64), cols [colTile + wc*64, +64).
  int colW = colTile + wc * 64;
  #pragma unroll
  for (int msub = 0; msub < 4; msub++) {
    #pragma unroll
    for (int reg = 0; reg < 4; reg++) {
      int grow = rowTile + wr * 64 + msub * 16 + 4 * q + reg;
      int lab = label[grow];
      float e = 0.f;
      #pragma unroll
      for (int ns = 0; ns < 4; ns++) {
        int col = colW + ns * 16 + l15;
        float v = acc[msub][ns][reg];
        if (col < C_CLS) {
          e += __expf(v);
          if (col == lab) tbf[grow] = v;   // bf16-GEMM cos at label position
        }
      }
      #pragma unroll
      for (int m = 1; m < 16; m <<= 1) e += __shfl_xor(e, m, 64);
      if (l15 == 0) pl[(size_t)grow * NCT2 + (size_t)ctile * 2 + wc] = e;
    }
  }
}

// Sum per-tile exp-sums -> row denominator, swap in margin logit, mean-reduce.
__global__ __launch_bounds__(256) void k_reduce(const float* __restrict__ pl,
                                               const float* __restrict__ tv,
                                               const float* __restrict__ tbf,
                                               float* __restrict__ out) {
  int row = blockIdx.x;
  int tid = threadIdx.x;
  float s = 0.f;
  for (int j = tid; j < NCT2; j += 256) s += pl[(size_t)row * NCT2 + j];
  __shared__ float sb[256];
  sb[tid] = s;
  __syncthreads();
  for (int k = 128; k > 0; k >>= 1) {
    if (tid < k) sb[tid] += sb[tid + k];
    __syncthreads();
  }
  if (tid == 0) {
    float S = sb[0];
    float t = tv[row];
    float tb = tbf[row];
    float sint = sqrtf(fmaxf(0.f, 1.f - t * t));
    float cosm = t * COS_M - sint * SIN_M;
    float Sp = S - __expf(tb) + __expf(cosm);   // replace target logit
    float loss = logf(Sp) - cosm;
    atomicAdd(out, loss * (1.0f / N_ROWS));
  }
}

extern "C" void kernel_launch(void* const* d_in, const int* in_sizes, int n_in,
                              void* d_out, int out_size, void* d_ws, size_t ws_size,
                              hipStream_t stream) {
  const float* x = (const float*)d_in[0];
  const int* label = (const int*)d_in[1];
  const float* w = (const float*)d_in[2];
  float* out = (float*)d_out;
  char* ws = (char*)d_ws;

  size_t off = 0;
  unsigned short* nx = (unsigned short*)(ws + off); off += (size_t)N_ROWS * E_DIM * 2;  // 4 MB
  unsigned short* nw = (unsigned short*)(ws + off); off += (size_t)C_CLS * E_DIM * 2;   // 51.5 MB
  float* tv  = (float*)(ws + off); off += (size_t)N_ROWS * 4;
  float* tbf = (float*)(ws + off); off += (size_t)N_ROWS * 4;
  float* pl  = (float*)(ws + off); off += (size_t)N_ROWS * NCT2 * 4;                    // 12.9 MB

  hipMemsetAsync(d_out, 0, sizeof(float), stream);
  k_norm_w<<<(C_CLS + 3) / 4, 256, 0, stream>>>(w, nw);
  k_norm_x<<<N_ROWS, 256, 0, stream>>>(x, w, label, nx, tv);
  dim3 g(N_ROWS / 128, NTILE);
  k_gemm<<<g, 256, 0, stream>>>(nx, nw, label, pl, tbf);
  k_reduce<<<N_ROWS, 256, 0, stream>>>(pl, tv, tbf, out);
}